// Round 7
// baseline (334.387 us; speedup 1.0000x reference)
//
#include <hip/hip_runtime.h>
#include <math.h>

#define N_INIT 20000
#define LVLS   32
#define PP     1024
#define DD     64
#define DEE    128
#define N_TOT  (N_INIT + LVLS * PP)   // 52768
#define ND     (LVLS * PP)            // 32768 derived nodes
#define NBLK   256                    // 1 block/CU: co-residency guaranteed (round-5 proven)
#define NTHR   256
#define NTILES ((N_TOT + 63) / 64)    // 825 eval tiles

// ws layout:
// [0,128)   ctl: acc_i[4]={n_good,n_sel,cnt_pos,cnt_negok} @0, acc_f @16,
//                init_done @20, fin_done @24
// [128, 128+ND*4)              flags (derived-node ready flags)
// [128+ND*4, +ND*DD*4)         dstore (derived node vectors)
#define FLAGS_OFF  128
#define DSTORE_OFF (FLAGS_OFF + (size_t)ND * 4)
#define ZERO_BYTES (FLAGS_OFF + (size_t)ND * 4)

// ---- round-5-proven device-coherent accessors (AGENT scope -> MALL) ----
__device__ __forceinline__ int ldi(const int* p) {
    return __hip_atomic_load(p, __ATOMIC_RELAXED, __HIP_MEMORY_SCOPE_AGENT);
}
__device__ __forceinline__ float ldf(const float* p) {
    return __hip_atomic_load(p, __ATOMIC_RELAXED, __HIP_MEMORY_SCOPE_AGENT);
}
__device__ __forceinline__ void stf(float* p, float v) {
    __hip_atomic_store(p, v, __ATOMIC_RELAXED, __HIP_MEMORY_SCOPE_AGENT);
}
__device__ __forceinline__ void sti(int* p, int v) {
    __hip_atomic_store(p, v, __ATOMIC_RELAXED, __HIP_MEMORY_SCOPE_AGENT);
}
__device__ __forceinline__ void vm0() {
    asm volatile("s_waitcnt vmcnt(0)" ::: "memory");
}
__device__ __forceinline__ float softplusf(float x) {
    return fmaxf(x, 0.f) + log1pf(expf(-fabsf(x)));
}

__global__ __launch_bounds__(NTHR, 2) void persist3(
    const int* __restrict__ thax, const int* __restrict__ parents,
    const int* __restrict__ rules, const int* __restrict__ sel_mask,
    const int* __restrict__ good_mask, const float* __restrict__ init_table,
    const float* __restrict__ W_rule, const float* __restrict__ b_rule,
    const float* __restrict__ W1, const float* __restrict__ b1,
    const float* __restrict__ w2, const float* __restrict__ b2,
    char* __restrict__ ws, float* __restrict__ out)
{
    int*   acc_i     = (int*)ws;                    // [0..3]
    float* acc_f     = (float*)(ws + 16);
    int*   init_done = (int*)(ws + 20);
    int*   fin_done  = (int*)(ws + 24);
    int*   flags     = (int*)(ws + FLAGS_OFF);
    float* dstore    = (float*)(ws + DSTORE_OFF);

    const int b = blockIdx.x, t = threadIdx.x;
    const int lane = t & 63, wv = t >> 6;

    __shared__ int   lst[PP];              // 4 KB: node list for current (level,rule)
    __shared__ int   s_lcnt;
    __shared__ float peL[16][2 * DD];      // 8 KB: parent vectors for a 16-node chunk
    __shared__ float partial[4][16][DD];   // 16 KB
    __shared__ float sS[64][DD];           // 16 KB: eval tile
    __shared__ float logitL[64];

    // ---------------- phase 1: mask counts (round-5 verbatim) ----------------
    {
        int idx = b * NTHR + t;
        bool v = idx < N_TOT;
        bool sel  = v && sel_mask[idx] > 0;
        bool good = sel && good_mask[idx] > 0;
        unsigned long long ms = __ballot(sel), mg = __ballot(good);
        if (lane == 0) {
            if (mg) atomicAdd(&acc_i[0], (int)__popcll(mg));
            if (ms) atomicAdd(&acc_i[1], (int)__popcll(ms));
        }
    }
    vm0();
    __syncthreads();
    if (t == 0) atomicAdd(init_done, 1);

    // ---------------- phase 2: DAG levels as (level,rule) tasks ----------------
    // block b owns rule (b & 63) at levels {b>>6, +4, +8, ..., +28}
    const int rule = b & 63;
    const int l0   = b >> 6;

    // W fragment in registers: wave wv holds rows [wv*32, wv*32+32), col = lane
    float Wr[32];
    {
        const float* Wb = W_rule + ((size_t)rule * 128 + wv * 32) * 64 + lane;
#pragma unroll
        for (int i = 0; i < 32; ++i) Wr[i] = Wb[(size_t)i * 64];
    }

    for (int l = l0; l < LVLS; l += 4) {
        // build this level's node list for our rule
        if (t == 0) s_lcnt = 0;
        __syncthreads();
        for (int e = t; e < PP; e += NTHR)
            if (rules[l * PP + e] == rule) {
                int i = atomicAdd(&s_lcnt, 1);
                lst[i] = e;
            }
        __syncthreads();
        const int lcnt = s_lcnt;

        for (int c0 = 0; c0 < lcnt; c0 += 16) {
            const int m = (lcnt - c0 < 16) ? (lcnt - c0) : 16;
            // wait for derived parents (init parents always ready)
            for (int idx = t; idx < 2 * m; idx += NTHR) {
                int pid = parents[((size_t)l * PP + lst[c0 + (idx >> 1)]) * 2 + (idx & 1)];
                if (pid >= N_INIT) {
                    const int* fp = &flags[pid - N_INIT];
                    while (ldi(fp) == 0) __builtin_amdgcn_s_sleep(1);
                }
            }
            __syncthreads();
            // gather parent vectors: init -> plain cached load, derived -> sc1
            for (int idx = t; idx < m * 128; idx += NTHR) {
                int k = idx >> 7, i = idx & 127;
                int pid = parents[((size_t)l * PP + lst[c0 + k]) * 2 + (i >> 6)];
                float v;
                if (pid < N_INIT)
                    v = init_table[(size_t)thax[pid] * DD + (i & 63)];
                else
                    v = ldf(&dstore[(size_t)(pid - N_INIT) * DD + (i & 63)]);
                peL[k][i] = v;
            }
            __syncthreads();
            // compute partials: wave wv covers input rows [wv*32, wv*32+32)
            for (int k = 0; k < m; ++k) {
                const float* pk = &peL[k][wv * 32];
                float a0 = 0.f, a1 = 0.f, a2 = 0.f, a3 = 0.f;
#pragma unroll
                for (int i = 0; i < 32; i += 4) {
                    a0 = fmaf(pk[i + 0], Wr[i + 0], a0);
                    a1 = fmaf(pk[i + 1], Wr[i + 1], a1);
                    a2 = fmaf(pk[i + 2], Wr[i + 2], a2);
                    a3 = fmaf(pk[i + 3], Wr[i + 3], a3);
                }
                partial[wv][k][lane] = (a0 + a1) + (a2 + a3);
            }
            __syncthreads();
            // combine + bias + relu + publish (sc1)
            for (int idx = t; idx < m * DD; idx += NTHR) {
                int k = idx >> 6, j = idx & 63;
                float h = partial[0][k][j] + partial[1][k][j] +
                          partial[2][k][j] + partial[3][k][j] +
                          b_rule[rule * DD + j];
                stf(&dstore[((size_t)l * PP + lst[c0 + k]) * DD + j], fmaxf(h, 0.f));
            }
            vm0();              // each thread's stores at coherence point
            __syncthreads();    // => all waves' stores complete
            if (t < m) sti(&flags[l * PP + lst[c0 + t]], 1);
            __syncthreads();    // before LDS reuse
        }
    }

    // ---------------- phase 3: gate on mask counts ----------------
    if (t == 0) { while (ldi(init_done) < NBLK) __builtin_amdgcn_s_sleep(1); }
    __syncthreads();
    const int ng = ldi(&acc_i[0]);
    const int ns = ldi(&acc_i[1]);
    const int nn = ns - ng;
    const float pos_w = ng > 0 ? 0.85f / (float)ng : 1.0f;
    const float neg_w = nn > 0 ? 0.15f / (float)nn : 1.0f;

    // ---------------- phase 4: eval + loss (flag-gated tiles) ----------------
    const int g  = t & 31;
    const int n0 = t >> 5;
    const float4* __restrict__ W14 = (const float4*)W1;
    const float4 b1v = ((const float4*)b1)[g];
    const float4 w2v = ((const float4*)w2)[g];
    const float  b2v = b2[0];

    float loss = 0.f;
    int cp = 0, cn = 0;

    for (int tile = b; tile < NTILES; tile += NBLK) {
        const int base = tile * 64;
        const int nv = (N_TOT - base < 64) ? (N_TOT - base) : 64;
        if (t < nv) {
            int node = base + t;
            if (node >= N_INIT) {
                const int* fp = &flags[node - N_INIT];
                while (ldi(fp) == 0) __builtin_amdgcn_s_sleep(1);
            }
        }
        __syncthreads();
        for (int idx = t; idx < 64 * 16; idx += NTHR) {
            int n = idx >> 4, q = idx & 15;
            int node = base + n;
            float4 v = make_float4(0.f, 0.f, 0.f, 0.f);
            if (n < nv) {
                if (node < N_INIT) {
                    v = ((const float4*)init_table)[(size_t)thax[node] * 16 + q];
                } else {
                    const float* dp = &dstore[(size_t)(node - N_INIT) * DD + q * 4];
                    v.x = ldf(dp + 0); v.y = ldf(dp + 1);
                    v.z = ldf(dp + 2); v.w = ldf(dp + 3);
                }
            }
            ((float4*)sS[n])[q] = v;
        }
        __syncthreads();

        // round-5-proven eval math: 64 nodes, thread group g handles col quad g
        float4 a[8];
#pragma unroll
        for (int k = 0; k < 8; ++k) a[k] = b1v;
#pragma unroll
        for (int d4 = 0; d4 < 16; ++d4) {
            float4 w0  = W14[(d4 * 4 + 0) * 32 + g];
            float4 w1  = W14[(d4 * 4 + 1) * 32 + g];
            float4 w2q = W14[(d4 * 4 + 2) * 32 + g];
            float4 w3  = W14[(d4 * 4 + 3) * 32 + g];
#pragma unroll
            for (int k = 0; k < 8; ++k) {
                float4 s = ((const float4*)sS[n0 + 8 * k])[d4];
                a[k].x = fmaf(s.x, w0.x, a[k].x); a[k].y = fmaf(s.x, w0.y, a[k].y);
                a[k].z = fmaf(s.x, w0.z, a[k].z); a[k].w = fmaf(s.x, w0.w, a[k].w);
                a[k].x = fmaf(s.y, w1.x, a[k].x); a[k].y = fmaf(s.y, w1.y, a[k].y);
                a[k].z = fmaf(s.y, w1.z, a[k].z); a[k].w = fmaf(s.y, w1.w, a[k].w);
                a[k].x = fmaf(s.z, w2q.x, a[k].x); a[k].y = fmaf(s.z, w2q.y, a[k].y);
                a[k].z = fmaf(s.z, w2q.z, a[k].z); a[k].w = fmaf(s.z, w2q.w, a[k].w);
                a[k].x = fmaf(s.w, w3.x, a[k].x); a[k].y = fmaf(s.w, w3.y, a[k].y);
                a[k].z = fmaf(s.w, w3.z, a[k].z); a[k].w = fmaf(s.w, w3.w, a[k].w);
            }
        }
        float p[8];
#pragma unroll
        for (int k = 0; k < 8; ++k) {
            p[k] = fmaxf(a[k].x, 0.f) * w2v.x + fmaxf(a[k].y, 0.f) * w2v.y +
                   fmaxf(a[k].z, 0.f) * w2v.z + fmaxf(a[k].w, 0.f) * w2v.w;
#pragma unroll
            for (int off = 1; off < 32; off <<= 1)
                p[k] += __shfl_xor(p[k], off, 32);
        }
        if (g == 0) {
#pragma unroll
            for (int k = 0; k < 8; ++k)
                logitL[n0 + 8 * k] = p[k] + b2v;
        }
        __syncthreads();

        if (t < 64) {
            int node = base + t;
            bool valid = t < nv;
            float lg = logitL[t];
            bool sel  = valid && sel_mask[node] > 0;
            bool good = sel && good_mask[node] > 0;
            float bce = softplusf(lg) - lg * (good ? 1.f : 0.f);
            float w   = (good ? pos_w : neg_w) * (sel ? 1.f : 0.f);
            loss += valid ? w * bce : 0.f;
            cp += (good && lg >= 0.f) ? 1 : 0;
            cn += (sel && !good && lg < 0.f) ? 1 : 0;
        }
        __syncthreads();
    }

    // ---------------- phase 5: reduce + finalize (round-5 verbatim) ----------------
    if (t < 64) {
        float c = loss;
        int cpp = cp, cnn = cn;
#pragma unroll
        for (int off = 32; off; off >>= 1) {
            c   += __shfl_down(c, off, 64);
            cpp += __shfl_down(cpp, off, 64);
            cnn += __shfl_down(cnn, off, 64);
        }
        if (t == 0) {
            atomicAdd(acc_f, c);
            if (cpp) atomicAdd(&acc_i[2], cpp);
            if (cnn) atomicAdd(&acc_i[3], cnn);
            vm0();                                 // partials at coherence point
            int d = atomicAdd(fin_done, 1);
            if (d == NBLK - 1) {                   // last block finalizes
                int ng2 = ldi(&acc_i[0]);
                int ns2 = ldi(&acc_i[1]);
                int cp2 = ldi(&acc_i[2]);
                int cn2 = ldi(&acc_i[3]);
                float lf = ldf(acc_f);
                int nn2 = ns2 - ng2;
                out[0] = lf;
                out[1] = ng2 > 0 ? (float)cp2 / (float)ng2 : 1.0f;
                out[2] = nn2 > 0 ? (float)cn2 / (float)nn2 : 1.0f;
            }
        }
    }
}

extern "C" void kernel_launch(void* const* d_in, const int* in_sizes, int n_in,
                              void* d_out, int out_size, void* d_ws, size_t ws_size,
                              hipStream_t stream) {
    const int*   thax       = (const int*)d_in[0];
    const int*   parents    = (const int*)d_in[1];
    const int*   rules      = (const int*)d_in[2];
    const int*   sel_mask   = (const int*)d_in[3];
    const int*   good_mask  = (const int*)d_in[4];
    const float* init_table = (const float*)d_in[5];
    const float* W_rule     = (const float*)d_in[6];
    const float* b_rule     = (const float*)d_in[7];
    const float* W1         = (const float*)d_in[8];
    const float* b1         = (const float*)d_in[9];
    const float* w2         = (const float*)d_in[10];
    const float* b2         = (const float*)d_in[11];

    // zero ctl + flags each call (deterministic; round-5 proven)
    hipMemsetAsync(d_ws, 0, ZERO_BYTES, stream);

    persist3<<<NBLK, NTHR, 0, stream>>>(
        thax, parents, rules, sel_mask, good_mask, init_table,
        W_rule, b_rule, W1, b1, w2, b2,
        (char*)d_ws, (float*)d_out);
}

// Round 8
// 195.932 us; speedup vs baseline: 1.7067x; 1.7067x over previous
//
#include <hip/hip_runtime.h>
#include <math.h>

#define N_INIT 20000
#define LVLS   32
#define PP     1024
#define DD     64
#define DEE    128
#define N_TOT  (N_INIT + LVLS * PP)   // 52768
#define ND     (LVLS * PP)            // 32768 derived nodes
#define NBLK   512                    // 2 blocks/CU, co-resident via launch_bounds
#define NTHR   256
#define NPB    2                      // nodes per block per level (512*2 = 1024)
#define NTILES ((N_TOT + 63) / 64)    // 825 eval tiles

// ws layout:
// [0,128)  ctl: acc_i[4]={n_good,n_sel,cnt_pos,cnt_negok}@0, acc_f@16,
//               init_done@20, fin_done@24
// [128, 128+ND*4)        flags
// [128+ND*4, +ND*DD*4)   dstore
#define FLAGS_OFF  128
#define DSTORE_OFF (FLAGS_OFF + (size_t)ND * 4)
#define ZERO_BYTES (FLAGS_OFF + (size_t)ND * 4)

typedef unsigned long long ull;
union F2U { ull u; float2 f; };

// ---- round-5-proven device-coherent accessors (AGENT scope) ----
__device__ __forceinline__ int ldi(const int* p) {
    return __hip_atomic_load(p, __ATOMIC_RELAXED, __HIP_MEMORY_SCOPE_AGENT);
}
__device__ __forceinline__ float ldf(const float* p) {
    return __hip_atomic_load(p, __ATOMIC_RELAXED, __HIP_MEMORY_SCOPE_AGENT);
}
__device__ __forceinline__ void sti(int* p, int v) {
    __hip_atomic_store(p, v, __ATOMIC_RELAXED, __HIP_MEMORY_SCOPE_AGENT);
}
__device__ __forceinline__ ull ldull(const ull* p) {
    return __hip_atomic_load(p, __ATOMIC_RELAXED, __HIP_MEMORY_SCOPE_AGENT);
}
__device__ __forceinline__ void stull(ull* p, ull v) {
    __hip_atomic_store(p, v, __ATOMIC_RELAXED, __HIP_MEMORY_SCOPE_AGENT);
}
__device__ __forceinline__ void vm0() {
    asm volatile("s_waitcnt vmcnt(0)" ::: "memory");
}
__device__ __forceinline__ float softplusf(float x) {
    return fmaxf(x, 0.f) + log1pf(expf(-fabsf(x)));
}

__global__ __launch_bounds__(NTHR, 2) void persist4(
    const int* __restrict__ thax, const int* __restrict__ parents,
    const int* __restrict__ rules, const int* __restrict__ sel_mask,
    const int* __restrict__ good_mask, const float* __restrict__ init_table,
    const float* __restrict__ W_rule, const float* __restrict__ b_rule,
    const float* __restrict__ W1, const float* __restrict__ b1,
    const float* __restrict__ w2, const float* __restrict__ b2,
    char* __restrict__ ws, float* __restrict__ out)
{
    int*   acc_i     = (int*)ws;
    float* acc_f     = (float*)(ws + 16);
    int*   init_done = (int*)(ws + 20);
    int*   fin_done  = (int*)(ws + 24);
    int*   flags     = (int*)(ws + FLAGS_OFF);
    float* dstore    = (float*)(ws + DSTORE_OFF);
    ull*   dstore_u  = (ull*)dstore;

    const int b = blockIdx.x, t = threadIdx.x;
    const int lane = t & 63, wv = t >> 6;

    __shared__ float peL[NPB][2 * DD];   // 1 KB
    __shared__ float partial[4][DD];     // 1 KB
    __shared__ float sS[64][DD];         // 16 KB (eval)
    __shared__ float logitL[64];

    // ---------------- phase 1: mask counts (round-5 verbatim) ----------------
    {
        int idx = b * NTHR + t;
        bool v = idx < N_TOT;
        bool sel  = v && sel_mask[idx] > 0;
        bool good = sel && good_mask[idx] > 0;
        unsigned long long ms = __ballot(sel), mg = __ballot(good);
        if (lane == 0) {
            if (mg) atomicAdd(&acc_i[0], (int)__popcll(mg));
            if (ms) atomicAdd(&acc_i[1], (int)__popcll(ms));
        }
    }
    vm0();
    __syncthreads();
    if (t == 0) atomicAdd(init_done, 1);

    // ---------------- phase 2: 32 levels, 2 nodes/block/level ----------------
    const int nb0 = b * NPB;                       // node offset within level
    for (int l = 0; l < LVLS; ++l) {
        const size_t pb = ((size_t)l * PP + nb0) * 2;   // 4 parent slots
        // wait for derived parents
        if (t < 2 * NPB) {
            int pid = parents[pb + t];
            if (pid >= N_INIT) {
                const int* fp = &flags[pid - N_INIT];
                while (ldi(fp) == 0) __builtin_amdgcn_s_sleep(1);
            }
        }
        __syncthreads();
        // gather 4 parent rows (float2 granularity): 128 threads x 1 float2
        if (t < 128) {
            int row = t >> 5;          // 0..3: node = row>>1, parent = row&1
            int j   = t & 31;          // float2 index within row
            int pid = parents[pb + row];
            float2 v;
            if (pid < N_INIT) {
                v = ((const float2*)init_table)[(size_t)thax[pid] * 32 + j];
            } else {
                F2U cv; cv.u = ldull(&dstore_u[(size_t)(pid - N_INIT) * 32 + j]);
                v = cv.f;
            }
            ((float2*)&peL[row >> 1][(row & 1) * DD])[j] = v;
        }
        __syncthreads();
        // compute: waves {0,1}->node 0, {2,3}->node 1; half = wv&1 covers 64 rows
        {
            const int nv = wv >> 1, half = wv & 1;
            const int ru = rules[l * PP + nb0 + nv];
            const float4* __restrict__ W4 =
                (const float4*)W_rule + (size_t)ru * 2048 + (size_t)half * 64 * 16;
            const int q = lane & 15, r = lane >> 4;
            const float* pk = &peL[nv][half * DD];
            float4 acc = make_float4(0.f, 0.f, 0.f, 0.f);
#pragma unroll
            for (int i = 0; i < 16; ++i) {
                float4 w = W4[(i * 4 + r) * 16 + q];
                float  s = pk[i * 4 + r];
                acc.x = fmaf(s, w.x, acc.x);
                acc.y = fmaf(s, w.y, acc.y);
                acc.z = fmaf(s, w.z, acc.z);
                acc.w = fmaf(s, w.w, acc.w);
            }
#pragma unroll
            for (int off = 16; off <= 32; off <<= 1) {
                acc.x += __shfl_xor(acc.x, off, 64);
                acc.y += __shfl_xor(acc.y, off, 64);
                acc.z += __shfl_xor(acc.z, off, 64);
                acc.w += __shfl_xor(acc.w, off, 64);
            }
            if (r == 0) *(float4*)&partial[wv][4 * q] = acc;
        }
        __syncthreads();
        // combine + bias + relu + publish (packed 8B coherent stores)
        if (t < 64) {
            const int nv = t >> 5;
            const int j2 = t & 31;
            const int jj = j2 * 2;
            const int ru = rules[l * PP + nb0 + nv];
            float h0 = partial[2 * nv][jj]     + partial[2 * nv + 1][jj]
                     + b_rule[ru * DD + jj];
            float h1 = partial[2 * nv][jj + 1] + partial[2 * nv + 1][jj + 1]
                     + b_rule[ru * DD + jj + 1];
            F2U cv;
            cv.f.x = fmaxf(h0, 0.f);
            cv.f.y = fmaxf(h1, 0.f);
            stull(&dstore_u[((size_t)l * PP + nb0 + nv) * 32 + j2], cv.u);
        }
        vm0();              // storing threads' data at coherence point
        __syncthreads();    // => all publishes complete
        if (t < NPB) sti(&flags[l * PP + nb0 + t], 1);
        __syncthreads();    // before peL/partial reuse
    }

    // ---------------- phase 3: gate on mask counts ----------------
    if (t == 0) { while (ldi(init_done) < NBLK) __builtin_amdgcn_s_sleep(1); }
    __syncthreads();
    const int ng = ldi(&acc_i[0]);
    const int ns = ldi(&acc_i[1]);
    const int nn = ns - ng;
    const float pos_w = ng > 0 ? 0.85f / (float)ng : 1.0f;
    const float neg_w = nn > 0 ? 0.15f / (float)nn : 1.0f;

    // ---------------- phase 4: eval + loss (round-7-proven math) ----------------
    const int g  = t & 31;
    const int n0 = t >> 5;
    const float4* __restrict__ W14 = (const float4*)W1;
    const float4 b1v = ((const float4*)b1)[g];
    const float4 w2v = ((const float4*)w2)[g];
    const float  b2v = b2[0];

    float loss = 0.f;
    int cp = 0, cn = 0;

    for (int tile = b; tile < NTILES; tile += NBLK) {
        const int base = tile * 64;
        const int nv = (N_TOT - base < 64) ? (N_TOT - base) : 64;
        if (t < nv) {
            int node = base + t;
            if (node >= N_INIT) {
                const int* fp = &flags[node - N_INIT];
                while (ldi(fp) == 0) __builtin_amdgcn_s_sleep(1);
            }
        }
        __syncthreads();
        for (int idx = t; idx < 64 * 32; idx += NTHR) {   // float2 granularity
            int n = idx >> 5, j = idx & 31;
            int node = base + n;
            float2 v = make_float2(0.f, 0.f);
            if (n < nv) {
                if (node < N_INIT) {
                    v = ((const float2*)init_table)[(size_t)thax[node] * 32 + j];
                } else {
                    F2U cv; cv.u = ldull(&dstore_u[(size_t)(node - N_INIT) * 32 + j]);
                    v = cv.f;
                }
            }
            ((float2*)sS[n])[j] = v;
        }
        __syncthreads();

        float4 a[8];
#pragma unroll
        for (int k = 0; k < 8; ++k) a[k] = b1v;
#pragma unroll
        for (int d4 = 0; d4 < 16; ++d4) {
            float4 w0  = W14[(d4 * 4 + 0) * 32 + g];
            float4 w1  = W14[(d4 * 4 + 1) * 32 + g];
            float4 w2q = W14[(d4 * 4 + 2) * 32 + g];
            float4 w3  = W14[(d4 * 4 + 3) * 32 + g];
#pragma unroll
            for (int k = 0; k < 8; ++k) {
                float4 s = ((const float4*)sS[n0 + 8 * k])[d4];
                a[k].x = fmaf(s.x, w0.x, a[k].x); a[k].y = fmaf(s.x, w0.y, a[k].y);
                a[k].z = fmaf(s.x, w0.z, a[k].z); a[k].w = fmaf(s.x, w0.w, a[k].w);
                a[k].x = fmaf(s.y, w1.x, a[k].x); a[k].y = fmaf(s.y, w1.y, a[k].y);
                a[k].z = fmaf(s.y, w1.z, a[k].z); a[k].w = fmaf(s.y, w1.w, a[k].w);
                a[k].x = fmaf(s.z, w2q.x, a[k].x); a[k].y = fmaf(s.z, w2q.y, a[k].y);
                a[k].z = fmaf(s.z, w2q.z, a[k].z); a[k].w = fmaf(s.z, w2q.w, a[k].w);
                a[k].x = fmaf(s.w, w3.x, a[k].x); a[k].y = fmaf(s.w, w3.y, a[k].y);
                a[k].z = fmaf(s.w, w3.z, a[k].z); a[k].w = fmaf(s.w, w3.w, a[k].w);
            }
        }
        float p[8];
#pragma unroll
        for (int k = 0; k < 8; ++k) {
            p[k] = fmaxf(a[k].x, 0.f) * w2v.x + fmaxf(a[k].y, 0.f) * w2v.y +
                   fmaxf(a[k].z, 0.f) * w2v.z + fmaxf(a[k].w, 0.f) * w2v.w;
#pragma unroll
            for (int off = 1; off < 32; off <<= 1)
                p[k] += __shfl_xor(p[k], off, 32);
        }
        if (g == 0) {
#pragma unroll
            for (int k = 0; k < 8; ++k)
                logitL[n0 + 8 * k] = p[k] + b2v;
        }
        __syncthreads();

        if (t < 64) {
            int node = base + t;
            bool valid = t < nv;
            float lg = logitL[t];
            bool sel  = valid && sel_mask[node] > 0;
            bool good = sel && good_mask[node] > 0;
            float bce = softplusf(lg) - lg * (good ? 1.f : 0.f);
            float w   = (good ? pos_w : neg_w) * (sel ? 1.f : 0.f);
            loss += valid ? w * bce : 0.f;
            cp += (good && lg >= 0.f) ? 1 : 0;
            cn += (sel && !good && lg < 0.f) ? 1 : 0;
        }
        __syncthreads();
    }

    // ---------------- phase 5: reduce + finalize (round-5 verbatim) ----------------
    if (t < 64) {
        float c = loss;
        int cpp = cp, cnn = cn;
#pragma unroll
        for (int off = 32; off; off >>= 1) {
            c   += __shfl_down(c, off, 64);
            cpp += __shfl_down(cpp, off, 64);
            cnn += __shfl_down(cnn, off, 64);
        }
        if (t == 0) {
            atomicAdd(acc_f, c);
            if (cpp) atomicAdd(&acc_i[2], cpp);
            if (cnn) atomicAdd(&acc_i[3], cnn);
            vm0();
            int d = atomicAdd(fin_done, 1);
            if (d == NBLK - 1) {
                int ng2 = ldi(&acc_i[0]);
                int ns2 = ldi(&acc_i[1]);
                int cp2 = ldi(&acc_i[2]);
                int cn2 = ldi(&acc_i[3]);
                float lf = ldf(acc_f);
                int nn2 = ns2 - ng2;
                out[0] = lf;
                out[1] = ng2 > 0 ? (float)cp2 / (float)ng2 : 1.0f;
                out[2] = nn2 > 0 ? (float)cn2 / (float)nn2 : 1.0f;
            }
        }
    }
}

extern "C" void kernel_launch(void* const* d_in, const int* in_sizes, int n_in,
                              void* d_out, int out_size, void* d_ws, size_t ws_size,
                              hipStream_t stream) {
    const int*   thax       = (const int*)d_in[0];
    const int*   parents    = (const int*)d_in[1];
    const int*   rules      = (const int*)d_in[2];
    const int*   sel_mask   = (const int*)d_in[3];
    const int*   good_mask  = (const int*)d_in[4];
    const float* init_table = (const float*)d_in[5];
    const float* W_rule     = (const float*)d_in[6];
    const float* b_rule     = (const float*)d_in[7];
    const float* W1         = (const float*)d_in[8];
    const float* b1         = (const float*)d_in[9];
    const float* w2         = (const float*)d_in[10];
    const float* b2         = (const float*)d_in[11];

    hipMemsetAsync(d_ws, 0, ZERO_BYTES, stream);

    persist4<<<NBLK, NTHR, 0, stream>>>(
        thax, parents, rules, sel_mask, good_mask, init_table,
        W_rule, b_rule, W1, b1, w2, b2,
        (char*)d_ws, (float*)d_out);
}

// Round 9
// 180.381 us; speedup vs baseline: 1.8538x; 1.0862x over previous
//
#include <hip/hip_runtime.h>
#include <math.h>

#define N_INIT 20000
#define LVLS   32
#define PP     1024
#define DD     64
#define DEE    128
#define N_TOT  (N_INIT + LVLS * PP)   // 52768
#define ND     (LVLS * PP)            // 32768 derived nodes
#define NBLK   512                    // 2 blocks/CU, co-residency proven (round 8)
#define NTHR   256
#define NPB    2                      // nodes per block per level (512*2 = 1024)
#define NTILES ((N_TOT + 63) / 64)    // 825 eval tiles

// ws layout:
// [0,128)  ctl: acc_i[4]={n_good,n_sel,cnt_pos,cnt_negok}@0, acc_f@16,
//               init_done@20, fin_done@24
// [128, 128+ND*DD*4)   dstore  (memset 0xFF each call: negative-NaN sentinel)
#define DSTORE_OFF 128

typedef unsigned long long ull;
union F2U { ull u; float2 f; };
#define SENT_MASK 0x8000000080000000ULL
#define SIGN_CLR  0x7FFFFFFF7FFFFFFFULL

// ---- device-coherent accessors (AGENT scope -> coherence point), proven r5-r8 ----
__device__ __forceinline__ int ldi(const int* p) {
    return __hip_atomic_load(p, __ATOMIC_RELAXED, __HIP_MEMORY_SCOPE_AGENT);
}
__device__ __forceinline__ float ldf(const float* p) {
    return __hip_atomic_load(p, __ATOMIC_RELAXED, __HIP_MEMORY_SCOPE_AGENT);
}
__device__ __forceinline__ ull ldull(const ull* p) {
    return __hip_atomic_load(p, __ATOMIC_RELAXED, __HIP_MEMORY_SCOPE_AGENT);
}
__device__ __forceinline__ void stull(ull* p, ull v) {
    __hip_atomic_store(p, v, __ATOMIC_RELAXED, __HIP_MEMORY_SCOPE_AGENT);
}
__device__ __forceinline__ void vm0() {
    asm volatile("s_waitcnt vmcnt(0)" ::: "memory");
}
__device__ __forceinline__ float softplusf(float x) {
    return fmaxf(x, 0.f) + log1pf(expf(-fabsf(x)));
}
// speculative load of a published float2: retry while any sign bit set
__device__ __forceinline__ float2 ld_pub(const ull* p) {
    F2U cv;
    cv.u = ldull(p);
    while (cv.u & SENT_MASK) {
        __builtin_amdgcn_s_sleep(1);
        cv.u = ldull(p);
    }
    return cv.f;
}

__global__ __launch_bounds__(NTHR, 2) void persist5(
    const int* __restrict__ thax, const int* __restrict__ parents,
    const int* __restrict__ rules, const int* __restrict__ sel_mask,
    const int* __restrict__ good_mask, const float* __restrict__ init_table,
    const float* __restrict__ W_rule, const float* __restrict__ b_rule,
    const float* __restrict__ W1, const float* __restrict__ b1,
    const float* __restrict__ w2, const float* __restrict__ b2,
    char* __restrict__ ws, float* __restrict__ out)
{
    int*   acc_i     = (int*)ws;
    float* acc_f     = (float*)(ws + 16);
    int*   init_done = (int*)(ws + 20);
    int*   fin_done  = (int*)(ws + 24);
    ull*   dstore_u  = (ull*)(ws + DSTORE_OFF);

    const int b = blockIdx.x, t = threadIdx.x;
    const int lane = t & 63, wv = t >> 6;

    __shared__ float peL[NPB][2 * DD];   // 1 KB
    __shared__ float partial[4][DD];     // 1 KB
    __shared__ float sS[64][DD];         // 16 KB (eval)
    __shared__ float logitL[64];

    // ---------------- phase 1: mask counts (round-5 verbatim) ----------------
    {
        int idx = b * NTHR + t;
        bool v = idx < N_TOT;
        bool sel  = v && sel_mask[idx] > 0;
        bool good = sel && good_mask[idx] > 0;
        unsigned long long ms = __ballot(sel), mg = __ballot(good);
        if (lane == 0) {
            if (mg) atomicAdd(&acc_i[0], (int)__popcll(mg));
            if (ms) atomicAdd(&acc_i[1], (int)__popcll(ms));
        }
    }
    vm0();
    __syncthreads();
    if (t == 0) atomicAdd(init_done, 1);

    // ---------------- phase 2: 32 levels, sentinel-validated dataflow ----------------
    const int nb0 = b * NPB;                       // node offset within level
    for (int l = 0; l < LVLS; ++l) {
        const size_t pb = ((size_t)l * PP + nb0) * 2;   // 4 parent slots
        // gather 4 parent rows speculatively (data is its own ready-flag)
        if (t < 128) {
            int row = t >> 5;          // 0..3: node = row>>1, parent = row&1
            int j   = t & 31;          // float2 index within row
            int pid = parents[pb + row];
            float2 v;
            if (pid < N_INIT)
                v = ((const float2*)init_table)[(size_t)thax[pid] * 32 + j];
            else
                v = ld_pub(&dstore_u[(size_t)(pid - N_INIT) * 32 + j]);
            ((float2*)&peL[row >> 1][(row & 1) * DD])[j] = v;
        }
        __syncthreads();
        // compute: waves {0,1}->node 0, {2,3}->node 1; half = wv&1 covers 64 rows
        {
            const int nv = wv >> 1, half = wv & 1;
            const int ru = rules[l * PP + nb0 + nv];
            const float4* __restrict__ W4 =
                (const float4*)W_rule + (size_t)ru * 2048 + (size_t)half * 64 * 16;
            const int q = lane & 15, r = lane >> 4;
            const float* pk = &peL[nv][half * DD];
            float4 acc = make_float4(0.f, 0.f, 0.f, 0.f);
#pragma unroll
            for (int i = 0; i < 16; ++i) {
                float4 w = W4[(i * 4 + r) * 16 + q];
                float  s = pk[i * 4 + r];
                acc.x = fmaf(s, w.x, acc.x);
                acc.y = fmaf(s, w.y, acc.y);
                acc.z = fmaf(s, w.z, acc.z);
                acc.w = fmaf(s, w.w, acc.w);
            }
#pragma unroll
            for (int off = 16; off <= 32; off <<= 1) {
                acc.x += __shfl_xor(acc.x, off, 64);
                acc.y += __shfl_xor(acc.y, off, 64);
                acc.z += __shfl_xor(acc.z, off, 64);
                acc.w += __shfl_xor(acc.w, off, 64);
            }
            if (r == 0) *(float4*)&partial[wv][4 * q] = acc;
        }
        __syncthreads();
        // combine + bias + relu + publish (sign-cleared packed stores; fire-and-forget)
        if (t < 64) {
            const int nv = t >> 5;
            const int j2 = t & 31;
            const int jj = j2 * 2;
            const int ru = rules[l * PP + nb0 + nv];
            float h0 = partial[2 * nv][jj]     + partial[2 * nv + 1][jj]
                     + b_rule[ru * DD + jj];
            float h1 = partial[2 * nv][jj + 1] + partial[2 * nv + 1][jj + 1]
                     + b_rule[ru * DD + jj + 1];
            F2U cv;
            cv.f.x = fmaxf(h0, 0.f);
            cv.f.y = fmaxf(h1, 0.f);
            cv.u &= SIGN_CLR;      // kill any -0.0: published sign bits must be 0
            stull(&dstore_u[((size_t)l * PP + nb0 + nv) * 32 + j2], cv.u);
        }
        __syncthreads();           // partial[] reuse protection (next level's compute)
    }

    // ---------------- phase 3: gate on mask counts ----------------
    if (t == 0) { while (ldi(init_done) < NBLK) __builtin_amdgcn_s_sleep(1); }
    __syncthreads();
    const int ng = ldi(&acc_i[0]);
    const int ns = ldi(&acc_i[1]);
    const int nn = ns - ng;
    const float pos_w = ng > 0 ? 0.85f / (float)ng : 1.0f;
    const float neg_w = nn > 0 ? 0.15f / (float)nn : 1.0f;

    // ---------------- phase 4: eval + loss (round-7-proven math) ----------------
    const int g  = t & 31;
    const int n0 = t >> 5;
    const float4* __restrict__ W14 = (const float4*)W1;
    const float4 b1v = ((const float4*)b1)[g];
    const float4 w2v = ((const float4*)w2)[g];
    const float  b2v = b2[0];

    float loss = 0.f;
    int cp = 0, cn = 0;

    for (int tile = b; tile < NTILES; tile += NBLK) {
        const int base = tile * 64;
        const int nv = (N_TOT - base < 64) ? (N_TOT - base) : 64;
        for (int idx = t; idx < 64 * 32; idx += NTHR) {   // float2 granularity
            int n = idx >> 5, j = idx & 31;
            int node = base + n;
            float2 v = make_float2(0.f, 0.f);
            if (n < nv) {
                if (node < N_INIT)
                    v = ((const float2*)init_table)[(size_t)thax[node] * 32 + j];
                else
                    v = ld_pub(&dstore_u[(size_t)(node - N_INIT) * 32 + j]);
            }
            ((float2*)sS[n])[j] = v;
        }
        __syncthreads();

        float4 a[8];
#pragma unroll
        for (int k = 0; k < 8; ++k) a[k] = b1v;
#pragma unroll
        for (int d4 = 0; d4 < 16; ++d4) {
            float4 w0  = W14[(d4 * 4 + 0) * 32 + g];
            float4 w1  = W14[(d4 * 4 + 1) * 32 + g];
            float4 w2q = W14[(d4 * 4 + 2) * 32 + g];
            float4 w3  = W14[(d4 * 4 + 3) * 32 + g];
#pragma unroll
            for (int k = 0; k < 8; ++k) {
                float4 s = ((const float4*)sS[n0 + 8 * k])[d4];
                a[k].x = fmaf(s.x, w0.x, a[k].x); a[k].y = fmaf(s.x, w0.y, a[k].y);
                a[k].z = fmaf(s.x, w0.z, a[k].z); a[k].w = fmaf(s.x, w0.w, a[k].w);
                a[k].x = fmaf(s.y, w1.x, a[k].x); a[k].y = fmaf(s.y, w1.y, a[k].y);
                a[k].z = fmaf(s.y, w1.z, a[k].z); a[k].w = fmaf(s.y, w1.w, a[k].w);
                a[k].x = fmaf(s.z, w2q.x, a[k].x); a[k].y = fmaf(s.z, w2q.y, a[k].y);
                a[k].z = fmaf(s.z, w2q.z, a[k].z); a[k].w = fmaf(s.z, w2q.w, a[k].w);
                a[k].x = fmaf(s.w, w3.x, a[k].x); a[k].y = fmaf(s.w, w3.y, a[k].y);
                a[k].z = fmaf(s.w, w3.z, a[k].z); a[k].w = fmaf(s.w, w3.w, a[k].w);
            }
        }
        float p[8];
#pragma unroll
        for (int k = 0; k < 8; ++k) {
            p[k] = fmaxf(a[k].x, 0.f) * w2v.x + fmaxf(a[k].y, 0.f) * w2v.y +
                   fmaxf(a[k].z, 0.f) * w2v.z + fmaxf(a[k].w, 0.f) * w2v.w;
#pragma unroll
            for (int off = 1; off < 32; off <<= 1)
                p[k] += __shfl_xor(p[k], off, 32);
        }
        if (g == 0) {
#pragma unroll
            for (int k = 0; k < 8; ++k)
                logitL[n0 + 8 * k] = p[k] + b2v;
        }
        __syncthreads();

        if (t < 64) {
            int node = base + t;
            bool valid = t < nv;
            float lg = logitL[t];
            bool sel  = valid && sel_mask[node] > 0;
            bool good = sel && good_mask[node] > 0;
            float bce = softplusf(lg) - lg * (good ? 1.f : 0.f);
            float w   = (good ? pos_w : neg_w) * (sel ? 1.f : 0.f);
            loss += valid ? w * bce : 0.f;
            cp += (good && lg >= 0.f) ? 1 : 0;
            cn += (sel && !good && lg < 0.f) ? 1 : 0;
        }
        __syncthreads();
    }

    // ---------------- phase 5: reduce + finalize (round-5 verbatim) ----------------
    if (t < 64) {
        float c = loss;
        int cpp = cp, cnn = cn;
#pragma unroll
        for (int off = 32; off; off >>= 1) {
            c   += __shfl_down(c, off, 64);
            cpp += __shfl_down(cpp, off, 64);
            cnn += __shfl_down(cnn, off, 64);
        }
        if (t == 0) {
            atomicAdd(acc_f, c);
            if (cpp) atomicAdd(&acc_i[2], cpp);
            if (cnn) atomicAdd(&acc_i[3], cnn);
            vm0();
            int d = atomicAdd(fin_done, 1);
            if (d == NBLK - 1) {
                int ng2 = ldi(&acc_i[0]);
                int ns2 = ldi(&acc_i[1]);
                int cp2 = ldi(&acc_i[2]);
                int cn2 = ldi(&acc_i[3]);
                float lf = ldf(acc_f);
                int nn2 = ns2 - ng2;
                out[0] = lf;
                out[1] = ng2 > 0 ? (float)cp2 / (float)ng2 : 1.0f;
                out[2] = nn2 > 0 ? (float)cn2 / (float)nn2 : 1.0f;
            }
        }
    }
}

extern "C" void kernel_launch(void* const* d_in, const int* in_sizes, int n_in,
                              void* d_out, int out_size, void* d_ws, size_t ws_size,
                              hipStream_t stream) {
    const int*   thax       = (const int*)d_in[0];
    const int*   parents    = (const int*)d_in[1];
    const int*   rules      = (const int*)d_in[2];
    const int*   sel_mask   = (const int*)d_in[3];
    const int*   good_mask  = (const int*)d_in[4];
    const float* init_table = (const float*)d_in[5];
    const float* W_rule     = (const float*)d_in[6];
    const float* b_rule     = (const float*)d_in[7];
    const float* W1         = (const float*)d_in[8];
    const float* b1         = (const float*)d_in[9];
    const float* w2         = (const float*)d_in[10];
    const float* b2         = (const float*)d_in[11];

    // ctl -> 0 ; dstore -> 0xFF (negative-NaN sentinel, sign bit 1)
    hipMemsetAsync(d_ws, 0, 128, stream);
    hipMemsetAsync((char*)d_ws + DSTORE_OFF, 0xFF, (size_t)ND * DD * 4, stream);

    persist5<<<NBLK, NTHR, 0, stream>>>(
        thax, parents, rules, sel_mask, good_mask, init_table,
        W_rule, b_rule, W1, b1, w2, b2,
        (char*)d_ws, (float*)d_out);
}